// Round 1
// baseline (701.770 us; speedup 1.0000x reference)
//
#include <hip/hip_runtime.h>
#include <cstdint>

typedef __attribute__((ext_vector_type(8))) short short8;
typedef __attribute__((ext_vector_type(4))) float floatx4;

#define TSEQ 256
#define TDEC 180
#define NIN  6
#define GROWS 16
#define NBLK (4096 / GROWS)

// split fp32 into hi/lo bf16 (truncation both times): x ~= hi + lo, err ~2^-16*|x|
__device__ __forceinline__ void split2(float x, uint16_t &h, uint16_t &l) {
  uint32_t u = __float_as_uint(x);
  h = (uint16_t)(u >> 16);
  float hf = __uint_as_float(u & 0xffff0000u);
  l = (uint16_t)(__float_as_uint(x - hf) >> 16);
}

__device__ __forceinline__ floatx4 mfma16(short8 a, short8 b, floatx4 c) {
  return __builtin_amdgcn_mfma_f32_16x16x32_bf16(a, b, c, 0, 0, 0);
}

__device__ __forceinline__ float sigm(float v) {
  return __builtin_amdgcn_rcpf(1.0f + __builtin_amdgcn_exp2f(-1.4426950408889634f * v));
}
__device__ __forceinline__ float tanh_fast(float v) {
  return 2.0f * __builtin_amdgcn_rcpf(1.0f + __builtin_amdgcn_exp2f(-2.8853900817779268f * v)) - 1.0f;
}

__global__ void __launch_bounds__(256, 1)
gru_persist(const float* __restrict__ x,
            const float* __restrict__ eWih0, const float* __restrict__ eWhh0,
            const float* __restrict__ ebih0, const float* __restrict__ ebhh0,
            const float* __restrict__ eWih1, const float* __restrict__ eWhh1,
            const float* __restrict__ ebih1, const float* __restrict__ ebhh1,
            const float* __restrict__ dWih0, const float* __restrict__ dWhh0,
            const float* __restrict__ dbih0, const float* __restrict__ dbhh0,
            const float* __restrict__ dWih1, const float* __restrict__ dWhh1,
            const float* __restrict__ dbih1, const float* __restrict__ dbhh1,
            const float* __restrict__ outW, const float* __restrict__ outB,
            float* __restrict__ out)
{
  // h0 staging rows: cols 0..63 = h0, 64..69 = x_t (enc) / prev (dec), 70..95 = zeros, 96..103 pad
  // row stride 104 elems (208B): 16B-aligned rows, ~2-way LDS banking on b128 reads
  __shared__ __align__(16) uint16_t s0h[2][16][104];
  __shared__ __align__(16) uint16_t s0l[2][16][104];
  __shared__ __align__(16) uint16_t s1h[2][16][72];
  __shared__ __align__(16) uint16_t s1l[2][16][72];
  __shared__ float cvp[16][4];

  const int tid  = threadIdx.x;
  const int wv   = tid >> 6;       // wave 0..3: owns tiles {wv, wv+4, wv+8} => u-range wv*16..wv*16+15
  const int lane = tid & 63;
  const int c    = lane & 15;      // MFMA: A row m / B,D col n
  const int q    = lane >> 4;      // quad
  const long base = (long)blockIdx.x * GROWS;

  // zero all staging (also guarantees A cols 70..95 are zero, never NaN garbage)
  for (int i = tid; i < 2 * 16 * 104; i += 256) { ((uint16_t*)s0h)[i] = 0; ((uint16_t*)s0l)[i] = 0; }
  for (int i = tid; i < 2 * 16 * 72;  i += 256) { ((uint16_t*)s1h)[i] = 0; ((uint16_t*)s1l)[i] = 0; }
  // x_0 into parity 0
  if (tid < 96) {
    int m = tid / 6, i = tid - m * 6;
    uint16_t h, l; split2(x[(base + m) * (TSEQ * NIN) + i], h, l);
    s0h[0][m][64 + i] = h; s0l[0][m][64 + i] = l;
  }

  // register-resident B fragments (hi/lo): [slot][kt]
  short8 B0h[3][3],  B0l[3][3];     // layer0: [Whh0 | Wih0-as-kt2]
  short8 B1ih[3][2], B1il[3][2];    // layer1 input weights
  short8 B1hh[3][2], B1hl[3][2];    // layer1 recurrent weights
  float bc_r, bc_z, bi_n, bh_n, bc1r, bc1z, bi1n, bh1n;

  auto load_phase = [&](const float* Whh0, const float* WihX, const float* Wih1,
                        const float* Whh1, bool enc) {
    #pragma unroll
    for (int s = 0; s < 3; s++) {
      const int n = (s * 4 + wv) * 16 + c;  // B col = j index in [0,192)
      #pragma unroll
      for (int kt = 0; kt < 2; kt++) {
        const int k0 = kt * 32 + q * 8;
        #pragma unroll
        for (int j = 0; j < 8; j++) {
          uint16_t h, l;
          split2(Whh0[n * 64 + k0 + j], h, l); B0h[s][kt][j]  = (short)h; B0l[s][kt][j]  = (short)l;
          split2(Wih1[n * 64 + k0 + j], h, l); B1ih[s][kt][j] = (short)h; B1il[s][kt][j] = (short)l;
          split2(Whh1[n * 64 + k0 + j], h, l); B1hh[s][kt][j] = (short)h; B1hl[s][kt][j] = (short)l;
        }
      }
      // kt=2: rows k=64.. hold the layer-0 input weights (x: 6 cols, prev: 1 col), rest zero
      #pragma unroll
      for (int j = 0; j < 8; j++) {
        float v = 0.0f;
        if (enc) { if (q == 0 && j < NIN) v = WihX[n * NIN + j]; }
        else     { if (q == 0 && j == 0)  v = WihX[n]; }
        uint16_t h, l; split2(v, h, l);
        B0h[s][2][j] = (short)h; B0l[s][2][j] = (short)l;
      }
    }
  };
  auto load_bias = [&](const float* bi0, const float* bh0, const float* bi1, const float* bh1) {
    const int jr = wv * 16 + c;
    bc_r = bi0[jr] + bh0[jr];
    bc_z = bi0[64 + jr] + bh0[64 + jr];
    bi_n = bi0[128 + jr]; bh_n = bh0[128 + jr];
    bc1r = bi1[jr] + bh1[jr];
    bc1z = bi1[64 + jr] + bh1[64 + jr];
    bi1n = bi1[128 + jr]; bh1n = bh1[128 + jr];
  };

  load_phase(eWhh0, eWih0, eWih1, eWhh1, true);
  load_bias(ebih0, ebhh0, ebih1, ebhh1);
  const float woutr = outW[wv * 16 + c];
  const float ob = outB[0];
  float h0r[4] = {0, 0, 0, 0}, h1r[4] = {0, 0, 0, 0};
  __syncthreads();

  // ============================ encoder ============================
  for (int t = 0; t < TSEQ; t++) {
    const int p = t & 1, pn = p ^ 1;

    float xpre = 0.0f; int xm = 0, xi = 0;
    if (tid < 96) {  // prefetch x_{t+1}
      xm = tid / 6; xi = tid - xm * 6;
      if (t + 1 < TSEQ) xpre = x[(base + xm) * (TSEQ * NIN) + (t + 1) * NIN + xi];
    }

    // ---- layer 0: [h0 | x_t] @ [Whh0 | Wih0]^T  (K=96 in 3 kt-tiles) ----
    floatx4 ar  = {bc_r, bc_r, bc_r, bc_r};
    floatx4 az  = {bc_z, bc_z, bc_z, bc_z};
    floatx4 agh = {bh_n, bh_n, bh_n, bh_n};   // gh_n (recurrent part, gets bhh_n)
    floatx4 agi = {bi_n, bi_n, bi_n, bi_n};   // gi_n (input part, gets bih_n)
    #pragma unroll
    for (int kt = 0; kt < 3; kt++) {
      const int kb = kt * 32 + q * 8;
      const short8 ah = *(const short8*)&s0h[p][c][kb];
      const short8 al = *(const short8*)&s0l[p][c][kb];
      ar = mfma16(ah, B0h[0][kt], ar); ar = mfma16(al, B0h[0][kt], ar); ar = mfma16(ah, B0l[0][kt], ar);
      az = mfma16(ah, B0h[1][kt], az); az = mfma16(al, B0h[1][kt], az); az = mfma16(ah, B0l[1][kt], az);
      if (kt < 2) { agh = mfma16(ah, B0h[2][kt], agh); agh = mfma16(al, B0h[2][kt], agh); agh = mfma16(ah, B0l[2][kt], agh); }
      else        { agi = mfma16(ah, B0h[2][kt], agi); agi = mfma16(al, B0h[2][kt], agi); agi = mfma16(ah, B0l[2][kt], agi); }
    }
    #pragma unroll
    for (int r4 = 0; r4 < 4; r4++) {
      const float rr = sigm(ar[r4]);
      const float zz = sigm(az[r4]);
      const float nn = tanh_fast(agi[r4] + rr * agh[r4]);
      const float hn = nn + zz * (h0r[r4] - nn);
      h0r[r4] = hn;
      uint16_t hh, hl; split2(hn, hh, hl);
      s0h[pn][q * 4 + r4][wv * 16 + c] = hh;
      s0l[pn][q * 4 + r4][wv * 16 + c] = hl;
    }
    __syncthreads();  // h0' visible for layer-1 gi

    // ---- layer 1: gi from h0' (parity pn), gh from h1 (parity p) ----
    floatx4 b_r = {bc1r, bc1r, bc1r, bc1r};
    floatx4 b_z = {bc1z, bc1z, bc1z, bc1z};
    floatx4 bgi = {bi1n, bi1n, bi1n, bi1n};
    floatx4 bgh = {bh1n, bh1n, bh1n, bh1n};
    #pragma unroll
    for (int kt = 0; kt < 2; kt++) {
      const int kb = kt * 32 + q * 8;
      const short8 ah = *(const short8*)&s0h[pn][c][kb];
      const short8 al = *(const short8*)&s0l[pn][c][kb];
      b_r = mfma16(ah, B1ih[0][kt], b_r); b_r = mfma16(al, B1ih[0][kt], b_r); b_r = mfma16(ah, B1il[0][kt], b_r);
      b_z = mfma16(ah, B1ih[1][kt], b_z); b_z = mfma16(al, B1ih[1][kt], b_z); b_z = mfma16(ah, B1il[1][kt], b_z);
      bgi = mfma16(ah, B1ih[2][kt], bgi); bgi = mfma16(al, B1ih[2][kt], bgi); bgi = mfma16(ah, B1il[2][kt], bgi);
      const short8 gh_ = *(const short8*)&s1h[p][c][kb];
      const short8 gl_ = *(const short8*)&s1l[p][c][kb];
      b_r = mfma16(gh_, B1hh[0][kt], b_r); b_r = mfma16(gl_, B1hh[0][kt], b_r); b_r = mfma16(gh_, B1hl[0][kt], b_r);
      b_z = mfma16(gh_, B1hh[1][kt], b_z); b_z = mfma16(gl_, B1hh[1][kt], b_z); b_z = mfma16(gh_, B1hl[1][kt], b_z);
      bgh = mfma16(gh_, B1hh[2][kt], bgh); bgh = mfma16(gl_, B1hh[2][kt], bgh); bgh = mfma16(gh_, B1hl[2][kt], bgh);
    }
    #pragma unroll
    for (int r4 = 0; r4 < 4; r4++) {
      const float rr = sigm(b_r[r4]);
      const float zz = sigm(b_z[r4]);
      const float nn = tanh_fast(bgi[r4] + rr * bgh[r4]);
      const float hn = nn + zz * (h1r[r4] - nn);
      h1r[r4] = hn;
      uint16_t hh, hl; split2(hn, hh, hl);
      s1h[pn][q * 4 + r4][wv * 16 + c] = hh;
      s1l[pn][q * 4 + r4][wv * 16 + c] = hl;
    }
    if (tid < 96) {  // stage x_{t+1} into next parity
      uint16_t hh, hl; split2(xpre, hh, hl);
      s0h[pn][xm][64 + xi] = hh; s0l[pn][xm][64 + xi] = hl;
    }
    __syncthreads();
  }

  // ============================ decoder ============================
  load_phase(dWhh0, dWih0, dWih1, dWhh1, false);
  load_bias(dbih0, dbhh0, dbih1, dbhh1);
  if (tid < 96) {  // clear stale x slots; prev0 = 0
    int m = tid / 6, i = tid - (tid / 6) * 6;
    s0h[0][m][64 + i] = 0; s0l[0][m][64 + i] = 0;
    s0h[1][m][64 + i] = 0; s0l[1][m][64 + i] = 0;
  }
  __syncthreads();

  for (int t = TSEQ; t < TSEQ + TDEC; t++) {
    const int p = t & 1, pn = p ^ 1;

    floatx4 ar  = {bc_r, bc_r, bc_r, bc_r};
    floatx4 az  = {bc_z, bc_z, bc_z, bc_z};
    floatx4 agh = {bh_n, bh_n, bh_n, bh_n};
    floatx4 agi = {bi_n, bi_n, bi_n, bi_n};
    #pragma unroll
    for (int kt = 0; kt < 3; kt++) {
      const int kb = kt * 32 + q * 8;
      const short8 ah = *(const short8*)&s0h[p][c][kb];
      const short8 al = *(const short8*)&s0l[p][c][kb];
      ar = mfma16(ah, B0h[0][kt], ar); ar = mfma16(al, B0h[0][kt], ar); ar = mfma16(ah, B0l[0][kt], ar);
      az = mfma16(ah, B0h[1][kt], az); az = mfma16(al, B0h[1][kt], az); az = mfma16(ah, B0l[1][kt], az);
      if (kt < 2) { agh = mfma16(ah, B0h[2][kt], agh); agh = mfma16(al, B0h[2][kt], agh); agh = mfma16(ah, B0l[2][kt], agh); }
      else        { agi = mfma16(ah, B0h[2][kt], agi); agi = mfma16(al, B0h[2][kt], agi); agi = mfma16(ah, B0l[2][kt], agi); }
    }
    #pragma unroll
    for (int r4 = 0; r4 < 4; r4++) {
      const float rr = sigm(ar[r4]);
      const float zz = sigm(az[r4]);
      const float nn = tanh_fast(agi[r4] + rr * agh[r4]);
      const float hn = nn + zz * (h0r[r4] - nn);
      h0r[r4] = hn;
      uint16_t hh, hl; split2(hn, hh, hl);
      s0h[pn][q * 4 + r4][wv * 16 + c] = hh;
      s0l[pn][q * 4 + r4][wv * 16 + c] = hl;
    }
    __syncthreads();

    floatx4 b_r = {bc1r, bc1r, bc1r, bc1r};
    floatx4 b_z = {bc1z, bc1z, bc1z, bc1z};
    floatx4 bgi = {bi1n, bi1n, bi1n, bi1n};
    floatx4 bgh = {bh1n, bh1n, bh1n, bh1n};
    #pragma unroll
    for (int kt = 0; kt < 2; kt++) {
      const int kb = kt * 32 + q * 8;
      const short8 ah = *(const short8*)&s0h[pn][c][kb];
      const short8 al = *(const short8*)&s0l[pn][c][kb];
      b_r = mfma16(ah, B1ih[0][kt], b_r); b_r = mfma16(al, B1ih[0][kt], b_r); b_r = mfma16(ah, B1il[0][kt], b_r);
      b_z = mfma16(ah, B1ih[1][kt], b_z); b_z = mfma16(al, B1ih[1][kt], b_z); b_z = mfma16(ah, B1il[1][kt], b_z);
      bgi = mfma16(ah, B1ih[2][kt], bgi); bgi = mfma16(al, B1ih[2][kt], bgi); bgi = mfma16(ah, B1il[2][kt], bgi);
      const short8 gh_ = *(const short8*)&s1h[p][c][kb];
      const short8 gl_ = *(const short8*)&s1l[p][c][kb];
      b_r = mfma16(gh_, B1hh[0][kt], b_r); b_r = mfma16(gl_, B1hh[0][kt], b_r); b_r = mfma16(gh_, B1hl[0][kt], b_r);
      b_z = mfma16(gh_, B1hh[1][kt], b_z); b_z = mfma16(gl_, B1hh[1][kt], b_z); b_z = mfma16(gh_, B1hl[1][kt], b_z);
      bgh = mfma16(gh_, B1hh[2][kt], bgh); bgh = mfma16(gl_, B1hh[2][kt], bgh); bgh = mfma16(gh_, B1hl[2][kt], bgh);
    }
    float hnew[4];
    #pragma unroll
    for (int r4 = 0; r4 < 4; r4++) {
      const float rr = sigm(b_r[r4]);
      const float zz = sigm(b_z[r4]);
      const float nn = tanh_fast(bgi[r4] + rr * bgh[r4]);
      const float hn = nn + zz * (h1r[r4] - nn);
      h1r[r4] = hn; hnew[r4] = hn;
      uint16_t hh, hl; split2(hn, hh, hl);
      s1h[pn][q * 4 + r4][wv * 16 + c] = hh;
      s1l[pn][q * 4 + r4][wv * 16 + c] = hl;
    }
    // ---- head: cv[m] = outb + sum_u h1'[m][u]*outW[u]; also feeds back as prev ----
    #pragma unroll
    for (int r4 = 0; r4 < 4; r4++) {
      float v = hnew[r4] * woutr;
      v += __shfl_xor(v, 1, 16);
      v += __shfl_xor(v, 2, 16);
      v += __shfl_xor(v, 4, 16);
      v += __shfl_xor(v, 8, 16);
      if (c == 0) cvp[q * 4 + r4][wv] = v;
    }
    __syncthreads();
    if (tid < 16) {
      const float cv = ob + cvp[tid][0] + cvp[tid][1] + cvp[tid][2] + cvp[tid][3];
      out[(base + tid) * TDEC + (t - TSEQ)] = cv;
      uint16_t hh, hl; split2(cv, hh, hl);
      s0h[pn][tid][64] = hh; s0l[pn][tid][64] = hl;
    }
    __syncthreads();
  }
}

extern "C" void kernel_launch(void* const* d_in, const int* in_sizes, int n_in,
                              void* d_out, int out_size, void* d_ws, size_t ws_size,
                              hipStream_t stream) {
  (void)in_sizes; (void)n_in; (void)d_ws; (void)ws_size; (void)out_size;
  const float* x     = (const float*)d_in[0];
  const float* eWih0 = (const float*)d_in[1];
  const float* eWhh0 = (const float*)d_in[2];
  const float* ebih0 = (const float*)d_in[3];
  const float* ebhh0 = (const float*)d_in[4];
  const float* eWih1 = (const float*)d_in[5];
  const float* eWhh1 = (const float*)d_in[6];
  const float* ebih1 = (const float*)d_in[7];
  const float* ebhh1 = (const float*)d_in[8];
  const float* dWih0 = (const float*)d_in[9];
  const float* dWhh0 = (const float*)d_in[10];
  const float* dbih0 = (const float*)d_in[11];
  const float* dbhh0 = (const float*)d_in[12];
  const float* dWih1 = (const float*)d_in[13];
  const float* dWhh1 = (const float*)d_in[14];
  const float* dbih1 = (const float*)d_in[15];
  const float* dbhh1 = (const float*)d_in[16];
  const float* outW  = (const float*)d_in[17];
  const float* outB  = (const float*)d_in[18];
  hipLaunchKernelGGL(gru_persist, dim3(NBLK), dim3(256), 0, stream,
                     x, eWih0, eWhh0, ebih0, ebhh0, eWih1, eWhh1, ebih1, ebhh1,
                     dWih0, dWhh0, dbih0, dbhh0, dWih1, dWhh1, dbih1, dbhh1,
                     outW, outB, (float*)d_out);
}